// Round 14
// baseline (988.321 us; speedup 1.0000x reference)
//
#include <hip/hip_runtime.h>
#include <cstdint>
#include <cstddef>

// ---------------------------------------------------------------------------
// EdgeCNN (DGCNN) 3-layer network. All GEMMs on MFMA (bf16 in, fp32 acc).
//   Factorization: concat[x_i, x_j-x_i] @ W1 = x_i@(W1a-W1b) + x_j@W1b
//   Edges counting-sorted by dst ONCE (max is order-independent -> output
//   bit-identical; scatter order nondeterminism is benign):
//     - A[dst] gather gains tile locality (R13: 380MB zero-reuse fetch)
//     - run-merged epilogue: 1 atomic per equal-dst run (R13: 268MB writes)
//   node_mfma: h @ wcat -> A (+b1), B planes (bf16), decode(keys)+ReLU fused.
//   edge_mfma: persistent blocks, reg-prefetch next tile during current MFMA.
// Weights pre-converted once to bf16 transposed+swizzled (wcg/wlg).
// Swizzle: 16B chunk c of row n stored at c^(n&7). Workspace ~59.4MB.
// ---------------------------------------------------------------------------

#define KEY_NEGINF 0x007FFFFFu  // fkey(-inf)

typedef __attribute__((ext_vector_type(8))) short bf16x8;
typedef __attribute__((ext_vector_type(4))) float f32x4;

__device__ __forceinline__ unsigned fkey(float f) {
  unsigned u = __float_as_uint(f);
  return (u & 0x80000000u) ? ~u : (u | 0x80000000u);
}
__device__ __forceinline__ float funkey(unsigned k) {
  unsigned u = (k & 0x80000000u) ? (k & 0x7FFFFFFFu) : ~k;
  return __uint_as_float(u);
}
__device__ __forceinline__ unsigned short f2bf(float f) {
  unsigned u = __float_as_uint(f);
  unsigned r = u + 0x7FFFu + ((u >> 16) & 1u);
  return (unsigned short)(r >> 16);
}
__device__ __forceinline__ float bflo(unsigned u) { return __uint_as_float(u << 16); }
__device__ __forceinline__ float bfhi(unsigned u) { return __uint_as_float(u & 0xFFFF0000u); }
__device__ __forceinline__ unsigned pack2(unsigned a, unsigned b) {
  float lo = fmaxf(bflo(a) + bflo(b), 0.f);
  float hi = fmaxf(bfhi(a) + bfhi(b), 0.f);
  return (unsigned)f2bf(lo) | ((unsigned)f2bf(hi) << 16);
}

// ---- edge sort by dst (counting sort) ----
__global__ void hist_dst(const int* __restrict__ ei, unsigned* __restrict__ hist, int E_) {
  int e = blockIdx.x * 256 + threadIdx.x;
  if (e < E_) atomicAdd(&hist[ei[E_ + e]], 1u);
}

// single-block chunked exclusive scan over n bins
__global__ void scan_bins(const unsigned* __restrict__ hist, unsigned* __restrict__ offs, int n) {
  __shared__ unsigned tmp[2][256];
  __shared__ unsigned carry;
  int t = threadIdx.x;
  if (t == 0) carry = 0;
  __syncthreads();
  for (int base = 0; base < n; base += 256) {
    unsigned v = (base + t < n) ? hist[base + t] : 0;
    int cur = 0;
    tmp[0][t] = v;
    __syncthreads();
    #pragma unroll
    for (int off = 1; off < 256; off <<= 1) {
      unsigned add = (t >= off) ? tmp[cur][t - off] : 0;
      __syncthreads();
      tmp[cur ^ 1][t] = tmp[cur][t] + add;
      __syncthreads();
      cur ^= 1;
    }
    unsigned incl = tmp[cur][t];
    if (base + t < n) offs[base + t] = carry + incl - v;
    __syncthreads();
    if (t == 255) carry += incl;
    __syncthreads();
  }
}

__global__ void scatter_edges(const int* __restrict__ ei, unsigned* __restrict__ offs,
                              int* __restrict__ esrc, int* __restrict__ edst, int E_) {
  int e = blockIdx.x * 256 + threadIdx.x;
  if (e >= E_) return;
  int s = ei[e], d = ei[E_ + e];
  unsigned pos = atomicAdd(&offs[d], 1u);
  esrc[pos] = s;
  edst[pos] = d;
}

// ---- weight prep (once per call) ----
__global__ void build_wcatbf(const float* __restrict__ w1, unsigned short* __restrict__ wcg) {
  int i = blockIdx.x * 256 + threadIdx.x;  // 4096 = 256n x 16c
  if (i >= 256 * 16) return;
  int n = i >> 4, c = i & 15;
  alignas(16) unsigned short ob[8];
  #pragma unroll
  for (int j = 0; j < 8; ++j) {
    int k = c * 8 + j;
    float v;
    if (n < 128) v = w1[(size_t)k * 128 + n] - w1[(size_t)(128 + k) * 128 + n];
    else         v = w1[(size_t)(128 + k) * 128 + (n - 128)];
    ob[j] = f2bf(v);
  }
  *reinterpret_cast<uint4*>(&wcg[n * 128 + ((c ^ (n & 7)) * 8)]) =
      *reinterpret_cast<const uint4*>(ob);
}

__global__ void build_w2bf(const float* __restrict__ w2, unsigned short* __restrict__ wlg) {
  int i = blockIdx.x * 256 + threadIdx.x;  // 2048 = 128n x 16c
  if (i >= 128 * 16) return;
  int n = i >> 4, c = i & 15;
  alignas(16) unsigned short ob[8];
  #pragma unroll
  for (int j = 0; j < 8; ++j) ob[j] = f2bf(w2[(size_t)(c * 8 + j) * 128 + n]);
  *reinterpret_cast<uint4*>(&wlg[n * 128 + ((c ^ (n & 7)) * 8)]) =
      *reinterpret_cast<const uint4*>(ob);
}

__global__ void build_wcat(const float* __restrict__ w1, float* __restrict__ wcat,
                           int F, int O) {
  int i = blockIdx.x * 256 + threadIdx.x;
  int total = F * O;
  if (i >= total) return;
  int k = i / O, o = i - k * O;
  float wa = w1[(size_t)k * O + o];
  float wb = w1[(size_t)(F + k) * O + o];
  wcat[(size_t)k * 2 * O + o] = wa - wb;
  wcat[(size_t)k * 2 * O + O + o] = wb;
}

__global__ void fill_u32(unsigned* __restrict__ p, unsigned v, size_t n) {
  size_t i = (size_t)blockIdx.x * blockDim.x + threadIdx.x;
  size_t stride = (size_t)gridDim.x * blockDim.x;
  for (; i < n; i += stride) p[i] = v;
}

__global__ void final_out(const unsigned* __restrict__ p, float* __restrict__ out, size_t n) {
  size_t i = (size_t)blockIdx.x * blockDim.x + threadIdx.x;
  size_t stride = (size_t)gridDim.x * blockDim.x;
  for (; i < n; i += stride) {
    unsigned k = p[i];
    out[i] = (k == KEY_NEGINF) ? 0.0f : funkey(k);
  }
}

// node MFMA: hin (fp32 x, or agg keys when decode=1) [N,128] @ wcat bf16 ->
// Abf (cols 0..127, +b1), Bbf (cols 128..255). LDS 80KB -> 2 blocks/CU.
__global__ __launch_bounds__(256, 2) void node_mfma(
    const unsigned* __restrict__ hin, int decode,
    const unsigned short* __restrict__ wcg, const float* __restrict__ b1,
    unsigned short* __restrict__ Abf, unsigned short* __restrict__ Bbf, int nN) {
  __shared__ unsigned short at[64 * 128];
  __shared__ unsigned short wt[256 * 128];
  int t = threadIdx.x;
  {
    const uint4* src = reinterpret_cast<const uint4*>(wcg);
    uint4* dst = reinterpret_cast<uint4*>(wt);
    for (int i = t; i < 4096; i += 256) dst[i] = src[i];
  }
  int m_base = blockIdx.x * 64;
  {
    int r = t >> 2, q = t & 3;
    int gm = min(m_base + r, nN - 1);
    const uint4* src = reinterpret_cast<const uint4*>(hin + (size_t)gm * 128);
    #pragma unroll
    for (int j = 0; j < 4; ++j) {
      int c = q + 4 * j;
      uint4 u0 = src[c * 2], u1 = src[c * 2 + 1];
      unsigned b[8] = {u0.x, u0.y, u0.z, u0.w, u1.x, u1.y, u1.z, u1.w};
      alignas(16) unsigned short ob[8];
      #pragma unroll
      for (int e = 0; e < 8; ++e) {
        float v = decode ? fmaxf(funkey(b[e]), 0.f) : __uint_as_float(b[e]);
        ob[e] = f2bf(v);
      }
      *reinterpret_cast<uint4*>(&at[r * 128 + ((c ^ (r & 7)) * 8)]) =
          *reinterpret_cast<const uint4*>(ob);
    }
  }
  __syncthreads();

  int l = t & 63, w = t >> 6;
  int strip = w * 16, lr = l & 15, lh = l >> 4;
  int arow = strip + lr, erow = strip + lh * 4;

  bf16x8 af[4];
  #pragma unroll
  for (int ks = 0; ks < 4; ++ks)
    af[ks] = *reinterpret_cast<const bf16x8*>(
        &at[arow * 128 + (((ks * 4 + lh) ^ (arow & 7)) * 8)]);

  #pragma unroll
  for (int nt = 0; nt < 16; ++nt) {
    f32x4 acc = (f32x4){0.f, 0.f, 0.f, 0.f};
    int n = nt * 16 + lr;
    #pragma unroll
    for (int ks = 0; ks < 4; ++ks) {
      bf16x8 bf = *reinterpret_cast<const bf16x8*>(
          &wt[n * 128 + (((ks * 4 + lh) ^ (n & 7)) * 8)]);
      acc = __builtin_amdgcn_mfma_f32_16x16x32_bf16(af[ks], bf, acc, 0, 0, 0);
    }
    bool isA = (n < 128);
    float bias = isA ? b1[n] : 0.f;
    int coln = isA ? n : n - 128;
    unsigned short* plane = isA ? Abf : Bbf;
    #pragma unroll
    for (int j = 0; j < 4; ++j) {
      int gm = m_base + erow + j;
      if (gm < nN) plane[(size_t)gm * 128 + coln] = f2bf(acc[j] + bias);
    }
  }
}

// edge MFMA, persistent, dst-sorted edges (esrc/edst).
// LDS: hs 16KB + wl 32KB + dstl -> 48.3KB => 3 blocks/CU.
__global__ __launch_bounds__(256, 3) void edge_mfma(
    const unsigned short* __restrict__ Abf, const unsigned short* __restrict__ Bbf,
    const int* __restrict__ esrc, const int* __restrict__ edst,
    const unsigned short* __restrict__ wlg,
    const float* __restrict__ b2, unsigned* __restrict__ aggk, int E_) {
  __shared__ unsigned short hs[64 * 128];
  __shared__ unsigned short wl[128 * 128];
  __shared__ int dstl[64];
  int t = threadIdx.x;
  {
    const uint4* src = reinterpret_cast<const uint4*>(wlg);
    uint4* dst = reinterpret_cast<uint4*>(wl);
    for (int i = t; i < 2048; i += 256) dst[i] = src[i];
  }
  int l = t & 63, w = t >> 6;
  int strip = w * 16, lr = l & 15, lh = l >> 4;
  int arow = strip + lr, erow = strip + lh * 4;
  int r = t >> 2, q = t & 3;

  float bb[8];
  #pragma unroll
  for (int nt = 0; nt < 8; ++nt) bb[nt] = b2[nt * 16 + lr];

  int ntiles = (E_ + 63) >> 6;
  int tile = blockIdx.x;
  uint4 ga[4], gb[4];
  int nd = 0;
  if (tile < ntiles) {
    int e = min(tile * 64 + r, E_ - 1);
    int s = esrc[e], d = edst[e];
    const uint4* Ar = reinterpret_cast<const uint4*>(Abf + (size_t)d * 128);
    const uint4* Br = reinterpret_cast<const uint4*>(Bbf + (size_t)s * 128);
    #pragma unroll
    for (int j = 0; j < 4; ++j) { ga[j] = Ar[q + 4 * j]; gb[j] = Br[q + 4 * j]; }
    nd = edst[min(tile * 64 + t, E_ - 1)];
  }

  for (; tile < ntiles; tile += gridDim.x) {
    __syncthreads();
    #pragma unroll
    for (int j = 0; j < 4; ++j) {
      int c = q + 4 * j;
      uint4 o;
      o.x = pack2(ga[j].x, gb[j].x);
      o.y = pack2(ga[j].y, gb[j].y);
      o.z = pack2(ga[j].z, gb[j].z);
      o.w = pack2(ga[j].w, gb[j].w);
      *reinterpret_cast<uint4*>(&hs[r * 128 + ((c ^ (r & 7)) * 8)]) = o;
    }
    if (t < 64) dstl[t] = nd;
    __syncthreads();

    int next = tile + gridDim.x;
    if (next < ntiles) {
      int e = min(next * 64 + r, E_ - 1);
      int s = esrc[e], d = edst[e];
      const uint4* Ar = reinterpret_cast<const uint4*>(Abf + (size_t)d * 128);
      const uint4* Br = reinterpret_cast<const uint4*>(Bbf + (size_t)s * 128);
      #pragma unroll
      for (int j = 0; j < 4; ++j) { ga[j] = Ar[q + 4 * j]; gb[j] = Br[q + 4 * j]; }
      nd = edst[min(next * 64 + t, E_ - 1)];
    }

    int drow[4];
    #pragma unroll
    for (int j = 0; j < 4; ++j) drow[j] = dstl[erow + j];
    unsigned cur[8][4];
    #pragma unroll
    for (int nt = 0; nt < 8; ++nt) {
      int col = nt * 16 + lr;
      #pragma unroll
      for (int j = 0; j < 4; ++j)
        cur[nt][j] = aggk[(size_t)drow[j] * 128 + col];
    }

    bf16x8 af[4];
    #pragma unroll
    for (int ks = 0; ks < 4; ++ks)
      af[ks] = *reinterpret_cast<const bf16x8*>(
          &hs[arow * 128 + (((ks * 4 + lh) ^ (arow & 7)) * 8)]);

    #pragma unroll
    for (int nt = 0; nt < 8; ++nt) {
      f32x4 acc = (f32x4){0.f, 0.f, 0.f, 0.f};
      int n = nt * 16 + lr;
      #pragma unroll
      for (int ks = 0; ks < 4; ++ks) {
        bf16x8 bf = *reinterpret_cast<const bf16x8*>(
            &wl[n * 128 + (((ks * 4 + lh) ^ (n & 7)) * 8)]);
        acc = __builtin_amdgcn_mfma_f32_16x16x32_bf16(af[ks], bf, acc, 0, 0, 0);
      }
      // run-merged epilogue: sorted dst => equal-dst runs within the 4 rows
      unsigned kcur = fkey(acc[0] + bb[nt]);
      #pragma unroll
      for (int j = 1; j < 4; ++j) {
        unsigned kn = fkey(acc[j] + bb[nt]);
        if (drow[j] == drow[j - 1]) {
          kcur = kcur > kn ? kcur : kn;
        } else {
          if (kcur > cur[nt][j - 1])
            atomicMax(aggk + (size_t)drow[j - 1] * 128 + n, kcur);
          kcur = kn;
        }
      }
      if (kcur > cur[nt][3])
        atomicMax(aggk + (size_t)drow[3] * 128 + n, kcur);
    }
  }
}

// Layer 2: hin = agg keys [N,128]; decode+ReLU fused. @ wcat2 [128,4] -> AB2.
__global__ void node_thin(const unsigned* __restrict__ hin, const float* __restrict__ wcat2,
                          const float* __restrict__ b1, float* __restrict__ AB2,
                          int nNodes) {
  __shared__ float w[128 * 4];
  int t = threadIdx.x;
  if (t < 128) *reinterpret_cast<float4*>(&w[t * 4]) =
      reinterpret_cast<const float4*>(wcat2)[t];
  __syncthreads();
  int node = blockIdx.x * 64 + (t >> 2);
  int o = t & 3;
  if (node >= nNodes) return;
  const uint4* h4 = reinterpret_cast<const uint4*>(hin + (size_t)node * 128);
  float acc = 0.f;
  #pragma unroll 8
  for (int kk = 0; kk < 32; ++kk) {
    uint4 x = h4[kk];
    acc += fmaxf(funkey(x.x), 0.f) * w[(kk * 4 + 0) * 4 + o];
    acc += fmaxf(funkey(x.y), 0.f) * w[(kk * 4 + 1) * 4 + o];
    acc += fmaxf(funkey(x.z), 0.f) * w[(kk * 4 + 2) * 4 + o];
    acc += fmaxf(funkey(x.w), 0.f) * w[(kk * 4 + 3) * 4 + o];
  }
  if (o < 2) acc += b1[o];
  AB2[(size_t)node * 4 + o] = acc;
}

__global__ void edge_small(const float* __restrict__ AB2, const int* __restrict__ esrc,
                           const int* __restrict__ edst,
                           const float* __restrict__ w2, const float* __restrict__ b2,
                           unsigned* __restrict__ aggk2, int E_) {
  int e = blockIdx.x * 256 + threadIdx.x;
  if (e >= E_) return;
  int s = esrc[e];
  int d = edst[e];
  float2 a = *reinterpret_cast<const float2*>(AB2 + (size_t)d * 4);
  float2 b = *reinterpret_cast<const float2*>(AB2 + (size_t)s * 4 + 2);
  float h0 = fmaxf(a.x + b.x, 0.f);
  float h1 = fmaxf(a.y + b.y, 0.f);
  float m0 = h0 * w2[0] + h1 * w2[2] + b2[0];
  float m1 = h0 * w2[1] + h1 * w2[3] + b2[1];
  atomicMax(aggk2 + (size_t)d * 2 + 0, fkey(m0));
  atomicMax(aggk2 + (size_t)d * 2 + 1, fkey(m1));
}

extern "C" void kernel_launch(void* const* d_in, const int* in_sizes, int n_in,
                              void* d_out, int out_size, void* d_ws, size_t ws_size,
                              hipStream_t stream) {
  const float* x    = (const float*)d_in[0];
  const int*   ei   = (const int*)d_in[1];
  const float* w1_0 = (const float*)d_in[2];
  const float* b1_0 = (const float*)d_in[3];
  const float* w2_0 = (const float*)d_in[4];
  const float* b2_0 = (const float*)d_in[5];
  const float* w1_1 = (const float*)d_in[6];
  const float* b1_1 = (const float*)d_in[7];
  const float* w2_1 = (const float*)d_in[8];
  const float* b2_1 = (const float*)d_in[9];
  const float* w1_2 = (const float*)d_in[10];
  const float* b1_2 = (const float*)d_in[11];
  const float* w2_2 = (const float*)d_in[12];
  const float* b2_2 = (const float*)d_in[13];

  const int N = in_sizes[0] / 128;
  const int E = in_sizes[1] / 2;

  // Workspace ~59.4 MB (52.7 proven OK in R10/R12; hard fail was at 78, R7):
  char* ws = (char*)d_ws;
  const size_t NB = (size_t)N * 128 * 4;  // 25.6 MB
  const size_t HB = (size_t)N * 128 * 2;  // 12.8 MB
  unsigned*       Z    = (unsigned*)(ws);
  unsigned short* Abf  = (unsigned short*)(ws + NB);
  unsigned short* Bbf  = (unsigned short*)(ws + NB + HB);
  float*    AB2  = (float*)(ws + NB + 2 * HB);
  unsigned* agg2 = (unsigned*)(ws + NB + 2 * HB + (size_t)N * 16);
  char*     wp   = ws + NB + 2 * HB + (size_t)N * 16 + (size_t)N * 8;
  unsigned short* wcg0 = (unsigned short*)(wp);                // 64 KB
  unsigned short* wcg1 = (unsigned short*)(wp + 65536);        // 64 KB
  unsigned short* wlg0 = (unsigned short*)(wp + 131072);       // 32 KB
  unsigned short* wlg1 = (unsigned short*)(wp + 163840);       // 32 KB
  float*          wc2  = (float*)(wp + 196608);                // 2 KB
  char*     sp   = wp + 198656;
  unsigned* hist = (unsigned*)(sp);                            // N u32
  unsigned* offs = (unsigned*)(sp + (size_t)N * 4);            // N u32
  int*      esrc = (int*)(sp + (size_t)N * 8);                 // E int
  int*      edst = (int*)(sp + (size_t)N * 8 + (size_t)E * 4); // E int

  const int nb = (N + 63) / 64;
  const int eb = (E + 63) / 64;
  const int egrid = eb < 768 ? eb : 768;
  const int epb = (E + 255) / 256;
  const size_t nH = (size_t)N * 128;

  // sort edges by dst (once; reused by both edge layers + edge_small)
  fill_u32<<<256, 256, 0, stream>>>(hist, 0u, (size_t)N);
  hist_dst<<<epb, 256, 0, stream>>>(ei, hist, E);
  scan_bins<<<1, 256, 0, stream>>>(hist, offs, N);
  scatter_edges<<<epb, 256, 0, stream>>>(ei, offs, esrc, edst, E);

  build_wcatbf<<<16, 256, 0, stream>>>(w1_0, wcg0);
  build_wcatbf<<<16, 256, 0, stream>>>(w1_1, wcg1);
  build_w2bf<<<8, 256, 0, stream>>>(w2_0, wlg0);
  build_w2bf<<<8, 256, 0, stream>>>(w2_1, wlg1);
  build_wcat<<<1, 256, 0, stream>>>(w1_2, wc2, 128, 2);

  // layer 0
  node_mfma<<<nb, 256, 0, stream>>>((const unsigned*)x, 0, wcg0, b1_0, Abf, Bbf, N);
  fill_u32<<<1024, 256, 0, stream>>>(Z, KEY_NEGINF, nH);
  edge_mfma<<<egrid, 256, 0, stream>>>(Abf, Bbf, esrc, edst, wlg0, b2_0, Z, E);

  // layer 1
  node_mfma<<<nb, 256, 0, stream>>>(Z, 1, wcg1, b1_1, Abf, Bbf, N);
  fill_u32<<<1024, 256, 0, stream>>>(Z, KEY_NEGINF, nH);
  edge_mfma<<<egrid, 256, 0, stream>>>(Abf, Bbf, esrc, edst, wlg1, b2_1, Z, E);

  // layer 2
  node_thin<<<nb, 256, 0, stream>>>(Z, wc2, b1_2, AB2, N);
  fill_u32<<<256, 256, 0, stream>>>(agg2, KEY_NEGINF, (size_t)N * 2);
  edge_small<<<epb, 256, 0, stream>>>(AB2, esrc, edst, w2_2, b2_2, agg2, E);
  final_out<<<((size_t)N * 2 + 255) / 256, 256, 0, stream>>>(agg2, (float*)d_out, (size_t)N * 2);
}